// Round 8
// baseline (1369.770 us; speedup 1.0000x reference)
//
#include <hip/hip_runtime.h>
#include <math.h>

#define NLOC 100

typedef __attribute__((ext_vector_type(8))) _Float16 half8;
typedef __attribute__((ext_vector_type(4))) float f32x4;

// ---------------- workspace layout (float offsets) ----------------
#define H_OFF     160000       // 51200 f32  (h, fp32)
#define QKV_OFF   211200       // 204800 f32 [100][2048]
#define H16_OFF   416000       // 25600 f32 slots = 100*512 f16 (h rounded to f16)
#define FFN_OFF   467200       // 102400 f32 slots = 100*2048 f16
#define ACTA_OFF  569600       // 320064 f32 slots = 640128 f16
#define ACTB_OFF  889664       // 320064
#define CWH_OFF   1209728      // 555776 f32 slots = 1111552 f16 conv wts L2..L10
#define WQKVT_OFF 1765824      // 6291456 f32 slots (12*2048*512 f16)
#define WOT_OFF   8057280      // 3145728
#define W1T_OFF   11203008     // 6291456
#define W2T_OFF   17494464     // 6291456

struct WPack { const float* w[9]; };   // conv layers 2..10

struct TJob {
    const float* src; unsigned short* dst;
    int K, N, mpl, lstride, base, tiles;
};

struct PrepParams {
    WPack wpk;
    const float* Wq; const float* Wk; const float* Wv; const float* Wo;
    const float* W1; const float* W2;
    const float* x; const float* cw1; const float* cb0;
    float* ws;
    unsigned short* aA;
};

// ---------------- fused weight prep + conv1 ----------------
// transpose: wave per 64(n) x 64(k) tile — each lane owns ONE output row's
// 128B contiguous chunk (full L2 sector dirty before eviction; fixes the
// 2.27x WRITE amplification measured in r7: 209MB vs 92MB compulsory).
__global__ __launch_bounds__(256) void prep_all(PrepParams PP)
{
    float* ws = PP.ws;
    unsigned short* cwh   = (unsigned short*)(ws + CWH_OFF);
    unsigned short* wqkvt = (unsigned short*)(ws + WQKVT_OFF);
    unsigned short* wot   = (unsigned short*)(ws + WOT_OFF);
    unsigned short* w1t   = (unsigned short*)(ws + W1T_OFF);
    unsigned short* w2t   = (unsigned short*)(ws + W2T_OFF);

    const int tid = threadIdx.x;
    const int gthread = blockIdx.x*256 + tid;
    const int nthreads = gridDim.x*256;
    const int gwave = gthread >> 6;
    const int nwaves = nthreads >> 6;
    const int lane = tid & 63;

    __shared__ TJob jobs[6];
    __shared__ float w1s[288];
    if (tid == 0) {
        jobs[0] = TJob{PP.Wq, wqkvt,  512,  128, 4, 2048*512, 0,         768};
        jobs[1] = TJob{PP.Wk, wqkvt,  512,  128, 4, 2048*512, 512*512,   768};
        jobs[2] = TJob{PP.Wv, wqkvt,  512,  256, 4, 2048*512, 1024*512, 1536};
        jobs[3] = TJob{PP.Wo, wot,   1024,  512, 1, 512*1024, 0,        1536};
        jobs[4] = TJob{PP.W1, w1t,    512, 2048, 1, 2048*512, 0,        3072};
        jobs[5] = TJob{PP.W2, w2t,   2048,  512, 1, 512*2048, 0,        3072};
    }
    for (int i = tid; i < 288; i += 256) {
        int c = i & 3;
        int r = i >> 2;
        int oc = r / 9, kk = r - oc*9;
        int ky = kk/3, kx = kk - ky*3;
        float v = 0.f;
        if (c < 3) v = PP.cw1[((oc*3 + c)*3 + ky)*3 + kx];
        w1s[i] = v;
    }
    __syncthreads();

    // conv weights L2..L10 -> f16 Bt[oc][Kpad], k = kk*Cin + ic
    {
        const int Cin[9]   = {8,16,32,32,64,64,128,128,256};
        const int shiftv[9]= {3,4,5,5,6,6,7,7,8};
        const int KSa[9]   = {3,3,3,3,3,3,3,3,2};
        const int Kpad[9]  = {96,160,288,288,576,576,1152,1152,1024};
        const int off[10]  = {0,1536,6656,15872,34304,71168,144896,292352,587264,1111552};
        for (int i = gthread; i < 1111552; i += nthreads) {
            int l = 0;
            while (i >= off[l+1]) ++l;
            int rem = i - off[l];
            int kp = Kpad[l];
            int oc = rem / kp;
            int k  = rem - oc*kp;
            int ci = Cin[l];
            int ic = k & (ci - 1);
            int kk = k >> shiftv[l];
            int ks = KSa[l], k2 = ks*ks;
            float v = 0.f;
            if (kk < k2) {
                int ky = kk / ks, kx = kk - ky*ks;
                v = PP.wpk.w[l][((oc*ci + ic)*ks + ky)*ks + kx];
            }
            _Float16 hv = (_Float16)v;
            cwh[i] = __builtin_bit_cast(unsigned short, hv);
        }
    }
    // transformer weight transposes: wave per 64(n) x 64(k) tile
    for (int t = gwave; t < 10752; t += nwaves) {
        int j = 0, rem = t;
        while (rem >= jobs[j].tiles) { rem -= jobs[j].tiles; ++j; }
        const int K = jobs[j].K, N = jobs[j].N;
        const int nb = N >> 6, kb = K >> 6;
        int mat = rem / (nb*kb);
        int r2  = rem - mat*(nb*kb);
        int n0  = (r2 % nb) << 6;
        int k0  = (r2 / nb) << 6;
        const float* s = jobs[j].src + (size_t)mat*K*N;
        int layer = mat / jobs[j].mpl, mi = mat - layer*jobs[j].mpl;
        unsigned short* d = jobs[j].dst + (size_t)layer*jobs[j].lstride + jobs[j].base + (size_t)mi*N*K;
        int nn = n0 + lane;
        unsigned short* dp = d + (size_t)nn*K + k0;      // lane's 128B chunk base
        #pragma unroll
        for (int b = 0; b < 8; ++b) {
            float v[8];
            #pragma unroll
            for (int kk = 0; kk < 8; ++kk) v[kk] = s[(size_t)(k0 + b*8 + kk)*N + nn];
            unsigned int u[4];
            #pragma unroll
            for (int q = 0; q < 4; ++q) {
                _Float16 a = (_Float16)v[2*q], b2 = (_Float16)v[2*q+1];
                u[q] = (unsigned int)__builtin_bit_cast(unsigned short, a)
                     | ((unsigned int)__builtin_bit_cast(unsigned short, b2) << 16);
            }
            *(uint4*)(dp + b*8) = make_uint4(u[0],u[1],u[2],u[3]);
        }
    }
    // conv1 directly from x (independent of the weight prep above)
    for (int idx = gthread; idx < 259200; idx += nthreads) {
        int oc = idx & 7;
        int r = idx >> 3;
        int p = r / 324;
        int s = r - p*324;
        int sy = s / 18, sx = s - sy*18;
        int pi = p/10, pj = p - pi*10;
        const float* xb = PP.x + (size_t)(pj*20 + sy)*200 + pi*20 + sx;
        float acc = 0.f;
        #pragma unroll
        for (int c = 0; c < 3; ++c) {
            const float* xc = xb + c*40000;
            #pragma unroll
            for (int ky = 0; ky < 3; ++ky)
                #pragma unroll
                for (int kx = 0; kx < 3; ++kx)
                    acc += xc[ky*200 + kx] * w1s[(oc*9 + ky*3 + kx)*4 + c];
        }
        acc += PP.cb0[oc];     // no relu after conv1
        _Float16 hv = (_Float16)acc;
        PP.aA[idx] = __builtin_bit_cast(unsigned short, hv);
    }
}

// ---------------- MFMA conv: wave per 16x16 tile, implicit im2col ----------------
template<int CIN, int COUT, int KS, int HIN, int WIN, int HOUT, int WOUT, int KPAD, int RELU, int LAST>
__global__ __launch_bounds__(256) void convM(const unsigned short* __restrict__ in,
    const unsigned short* __restrict__ wth, const float* __restrict__ bias,
    unsigned short* __restrict__ out, float* __restrict__ hout, unsigned short* __restrict__ h16out)
{
    constexpr int HW = HOUT*WOUT;
    constexpr int M = 100*HW;
    constexpr int MT = (M + 15)/16;
    constexpr int NT = COUT/16;
    int wave = threadIdx.x >> 6, lane = threadIdx.x & 63;
    int t = blockIdx.x*4 + wave;
    if (t >= MT*NT) return;
    int mt = t % MT, nt = t / MT;
    int mrow = lane & 15, quad = lane >> 4;
    int mg = mt*16 + mrow; if (mg >= M) mg = M - 1;
    int p = mg / HW, s = mg - p*HW;
    int sy = s / WOUT, sx = s - sy*WOUT;
    const unsigned short* ap = in + ((size_t)((p*HIN + sy)*WIN + sx))*CIN;
    const unsigned short* bp = wth + ((size_t)(nt*16 + mrow))*KPAD + quad*8;
    f32x4 acc = {0.f, 0.f, 0.f, 0.f};
    #pragma unroll
    for (int k0 = 0; k0 < KPAD; k0 += 32) {
        int k = k0 + quad*8;
        int kk = k / CIN; if (kk > KS*KS - 1) kk = KS*KS - 1;
        int ky = kk / KS, kx = kk - ky*KS;
        uint4 av = *(const uint4*)(ap + (ky*WIN + kx)*CIN + (k & (CIN-1)));
        uint4 bv = *(const uint4*)(bp + k0);
        acc = __builtin_amdgcn_mfma_f32_16x16x32_f16(
            __builtin_bit_cast(half8, av), __builtin_bit_cast(half8, bv), acc, 0, 0, 0);
    }
    int n = nt*16 + mrow;
    float bv = bias[n];
    #pragma unroll
    for (int r = 0; r < 4; ++r) {
        int m = mt*16 + quad*4 + r;
        if (m < M) {
            float v = acc[r] + bv;
            if (RELU) v = fmaxf(v, 0.f);
            if (LAST) {
                int pi = m / 10;
                float pos = 20.f * (float)pi;
                int dd = n & 255;
                float inv = powf(10000.f, (float)dd * (1.f/128.f));
                float ang = pos / inv;
                v += (n < 256) ? sinf(ang) : cosf(ang);
                hout[(size_t)m*512 + n] = v;
                _Float16 hv = (_Float16)v;
                h16out[(size_t)m*512 + n] = __builtin_bit_cast(unsigned short, hv);
            } else {
                _Float16 hv = (_Float16)v;
                out[(size_t)m*COUT + n] = __builtin_bit_cast(unsigned short, hv);
            }
        }
    }
}

// ---------------- MFMA GEMM (transformer) ----------------
// CMODE: 0 = plain store (if C), 1 = atomicAdd, 2 = residual store (C += acc, single pass)
template<int ABITS, int RELU, int CMODE, int STOREH>
__global__ __launch_bounds__(256) void gemm16(
    const void* __restrict__ Av, int lda,
    const unsigned short* __restrict__ Bt, int K,
    const float* __restrict__ bias,
    float* __restrict__ C, unsigned short* __restrict__ Ch, int ldc,
    int kchunk)
{
    int lane = threadIdx.x & 63;
    int wave = threadIdx.x >> 6;
    int mrow = lane & 15, quad = lane >> 4;
    int n0 = blockIdx.x*64 + wave*16;
    int m0 = blockIdx.y*16;
    int arow = m0 + mrow; if (arow > 99) arow = 99;
    int k0 = blockIdx.z * kchunk;
    const unsigned short* bp = Bt + (size_t)(n0 + mrow)*K + quad*8 + k0;
    f32x4 acc = {0.f, 0.f, 0.f, 0.f};
    if (ABITS == 16) {
        const unsigned short* ap = (const unsigned short*)Av + (size_t)arow*lda + quad*8 + k0;
        for (int k = 0; k < kchunk; k += 32) {
            uint4 au = *(const uint4*)(ap + k);
            uint4 bu = *(const uint4*)(bp + k);
            acc = __builtin_amdgcn_mfma_f32_16x16x32_f16(
                __builtin_bit_cast(half8, au), __builtin_bit_cast(half8, bu), acc, 0, 0, 0);
        }
    } else {
        const float* ap = (const float*)Av + (size_t)arow*lda + quad*8 + k0;
        for (int k = 0; k < kchunk; k += 32) {
            float4 f0 = *(const float4*)(ap + k);
            float4 f1 = *(const float4*)(ap + k + 4);
            half8 af;
            af[0] = (_Float16)f0.x; af[1] = (_Float16)f0.y;
            af[2] = (_Float16)f0.z; af[3] = (_Float16)f0.w;
            af[4] = (_Float16)f1.x; af[5] = (_Float16)f1.y;
            af[6] = (_Float16)f1.z; af[7] = (_Float16)f1.w;
            uint4 bu = *(const uint4*)(bp + k);
            acc = __builtin_amdgcn_mfma_f32_16x16x32_f16(
                af, __builtin_bit_cast(half8, bu), acc, 0, 0, 0);
        }
    }
    int n = n0 + mrow;
    float bv = (bias != nullptr && blockIdx.z == 0) ? bias[n] : 0.f;
    #pragma unroll
    for (int r = 0; r < 4; ++r) {
        int row = m0 + quad*4 + r;
        if (row < 100) {
            float v = acc[r] + bv;
            if (RELU) v = fmaxf(v, 0.f);
            if (CMODE == 2) v += C[(size_t)row*ldc + n];
            if (CMODE == 1) atomicAdd(&C[(size_t)row*ldc + n], v);
            else if (C != nullptr) C[(size_t)row*ldc + n] = v;
            if (STOREH) {
                _Float16 hv = (_Float16)v;
                Ch[(size_t)row*ldc + n] = __builtin_bit_cast(unsigned short, hv);
            }
        }
    }
}

// ---------------- fused attention + O-projection + residual ----------------
// one block per query row (100 blocks x 1024 threads); verified r5-r7.
// Emits h (f32) and h16 (f16-rounded) for FFN1's f16 A-path.
__global__ __launch_bounds__(1024) void attn_fused(const float* __restrict__ qkv,
    const unsigned short* __restrict__ Bo, float* __restrict__ h, unsigned short* __restrict__ h16)
{
    __shared__ float qs[512];       // staged q row
    __shared__ float oc_s[1024];    // concat attn output (f16-rounded)
    __shared__ float pb[4][128];    // scores per head
    __shared__ float rr[8];         // max/sum per head
    const int nn = blockIdx.x;
    const int tid = threadIdx.x;
    const int hh = tid >> 8;        // head 0..3
    const int t  = tid & 255;
    if (tid < 256) {
        float2 qv = *(const float2*)(qkv + (size_t)nn*2048 + tid*2);
        qs[tid*2] = qv.x; qs[tid*2 + 1] = qv.y;
    }
    __syncthreads();
    float sv = 0.f;
    if (t < 100) {
        const float4* q4 = (const float4*)(qs + hh*128);
        const float4* kp = (const float4*)(qkv + (size_t)t*2048 + 512 + hh*128);
        float s0=0.f, s1=0.f, s2=0.f, s3=0.f;
        #pragma unroll 8
        for (int j = 0; j < 32; ++j) {
            float4 a = q4[j], b = kp[j];
            s0 += a.x*b.x; s1 += a.y*b.y; s2 += a.z*b.z; s3 += a.w*b.w;
        }
        sv = (s0+s1+s2+s3) * 0.1f;    // scale = 1/sqrt(N_LOC) quirk
        pb[hh][t] = sv;
    }
    __syncthreads();
    if (t < 64) {                     // one aligned wave per head
        float m = fmaxf(pb[hh][t], (t+64 < 100) ? pb[hh][t+64] : -1e30f);
        for (int o = 32; o > 0; o >>= 1) m = fmaxf(m, __shfl_down(m, o));
        if (t == 0) rr[hh] = m;
    }
    __syncthreads();
    float mx = rr[hh];
    if (t < 100) pb[hh][t] = expf(sv - mx);
    __syncthreads();
    if (t < 64) {
        float s2 = pb[hh][t] + ((t+64 < 100) ? pb[hh][t+64] : 0.f);
        for (int o = 32; o > 0; o >>= 1) s2 += __shfl_down(s2, o);
        if (t == 0) rr[4+hh] = s2;
    }
    __syncthreads();
    float inv = 1.f / rr[4+hh];
    // PV: all 1024 threads, output element (hh, t)
    {
        const float* vp = qkv + 1024 + hh*256 + t;
        float a0 = 0.f;
        #pragma unroll 4
        for (int m = 0; m < 100; ++m) a0 += pb[hh][m] * vp[(size_t)m*2048];
        // round through f16 to match the reference path's ocat precision
        oc_s[hh*256 + t] = (float)(_Float16)(a0 * inv);
    }
    __syncthreads();
    // O-projection + residual: 512 outputs over threads 0..511
    if (tid < 512) {
        const unsigned short* wr = Bo + (size_t)tid*1024;
        float acc = 0.f;
        #pragma unroll 4
        for (int k2 = 0; k2 < 1024; k2 += 8) {
            uint4 wu = *(const uint4*)(wr + k2);
            half8 wf = __builtin_bit_cast(half8, wu);
            acc += oc_s[k2+0]*(float)wf[0] + oc_s[k2+1]*(float)wf[1]
                 + oc_s[k2+2]*(float)wf[2] + oc_s[k2+3]*(float)wf[3]
                 + oc_s[k2+4]*(float)wf[4] + oc_s[k2+5]*(float)wf[5]
                 + oc_s[k2+6]*(float)wf[6] + oc_s[k2+7]*(float)wf[7];
        }
        float hv = h[(size_t)nn*512 + tid] + acc;
        h[(size_t)nn*512 + tid] = hv;
        _Float16 hf = (_Float16)hv;
        h16[(size_t)nn*512 + tid] = __builtin_bit_cast(unsigned short, hf);
    }
}

// ---------------- final copy ----------------
__global__ __launch_bounds__(256) void copyk(const float* __restrict__ s, float* __restrict__ d, int n)
{
    int i = blockIdx.x*256 + threadIdx.x;
    if (i < n) d[i] = s[i];
}

// ---------------- launch ----------------
extern "C" void kernel_launch(void* const* d_in, const int* in_sizes, int n_in,
                              void* d_out, int out_size, void* d_ws, size_t ws_size,
                              hipStream_t stream)
{
    const float* x = (const float*)d_in[0];
    const float* cw1 = (const float*)d_in[1];
    const float* cb[10];
    WPack wpk;
    for (int i = 0; i < 10; ++i) cb[i] = (const float*)d_in[2 + 2*i];
    for (int i = 0; i < 9; ++i)  wpk.w[i] = (const float*)d_in[3 + 2*i];  // layers 2..10
    const float* Wq = (const float*)d_in[21];
    const float* Wk = (const float*)d_in[22];
    const float* Wv = (const float*)d_in[23];
    const float* Wo = (const float*)d_in[24];
    const float* W1 = (const float*)d_in[25];
    const float* b1 = (const float*)d_in[26];
    const float* W2 = (const float*)d_in[27];
    const float* b2 = (const float*)d_in[28];

    float* ws = (float*)d_ws;
    float* h   = ws + H_OFF;
    float* qkv = ws + QKV_OFF;
    unsigned short* h16  = (unsigned short*)(ws + H16_OFF);
    unsigned short* ffn  = (unsigned short*)(ws + FFN_OFF);
    unsigned short* aA   = (unsigned short*)(ws + ACTA_OFF);
    unsigned short* aB   = (unsigned short*)(ws + ACTB_OFF);
    unsigned short* cwh  = (unsigned short*)(ws + CWH_OFF);
    unsigned short* wqkvt = (unsigned short*)(ws + WQKVT_OFF);
    unsigned short* wot   = (unsigned short*)(ws + WOT_OFF);
    unsigned short* w1t   = (unsigned short*)(ws + W1T_OFF);
    unsigned short* w2t   = (unsigned short*)(ws + W2T_OFF);

    // fused weight prep + conv1 (replaces 9 kernels)
    PrepParams PP;
    PP.wpk = wpk;
    PP.Wq = Wq; PP.Wk = Wk; PP.Wv = Wv; PP.Wo = Wo; PP.W1 = W1; PP.W2 = W2;
    PP.x = x; PP.cw1 = cw1; PP.cb0 = cb[0];
    PP.ws = ws; PP.aA = aA;
    prep_all<<<2048, 256, 0, stream>>>(PP);

    // conv stack
    convM<8,  16, 3,18,18,16,16,  96,1,0><<<400, 256, 0, stream>>>(aA, cwh + 0,      cb[1], aB, nullptr, nullptr);
    convM<16, 32, 3,16,16,14,14, 160,0,0><<<613, 256, 0, stream>>>(aB, cwh + 1536,   cb[2], aA, nullptr, nullptr);
    convM<32, 32, 3,14,14,12,12, 288,1,0><<<450, 256, 0, stream>>>(aA, cwh + 6656,   cb[3], aB, nullptr, nullptr);
    convM<32, 64, 3,12,12,10,10, 288,1,0><<<625, 256, 0, stream>>>(aB, cwh + 15872,  cb[4], aA, nullptr, nullptr);
    convM<64, 64, 3,10,10, 8, 8, 576,1,0><<<400, 256, 0, stream>>>(aA, cwh + 34304,  cb[5], aB, nullptr, nullptr);
    convM<64,128, 3, 8, 8, 6, 6, 576,1,0><<<450, 256, 0, stream>>>(aB, cwh + 71168,  cb[6], aA, nullptr, nullptr);
    convM<128,128,3, 6, 6, 4, 4,1152,1,0><<<200, 256, 0, stream>>>(aA, cwh + 144896, cb[7], aB, nullptr, nullptr);
    convM<128,256,3, 4, 4, 2, 2,1152,1,0><<<100, 256, 0, stream>>>(aB, cwh + 292352, cb[8], aA, nullptr, nullptr);
    convM<256,512,2, 2, 2, 1, 1,1024,0,1><<<56,  256, 0, stream>>>(aA, cwh + 587264, cb[9], nullptr, h, h16);

    // transformer: 4 kernels per layer; all GEMM A-operands on the f16 path
    for (int n = 0; n < 12; ++n) {
        const unsigned short* Bq  = wqkvt + (size_t)n * 2048 * 512;
        const unsigned short* Bo  = wot   + (size_t)n * 512 * 1024;
        const unsigned short* Bf1 = w1t   + (size_t)n * 2048 * 512;
        const unsigned short* Bf2 = w2t   + (size_t)n * 512 * 2048;
        gemm16<16,0,0,0><<<dim3(32, 7, 1), 256, 0, stream>>>(h16, 512, Bq, 512,
            nullptr, qkv, nullptr, 2048, 512);
        attn_fused<<<100, 1024, 0, stream>>>(qkv, Bo, h, h16);
        gemm16<16,1,0,1><<<dim3(32, 7, 1), 256, 0, stream>>>(h16, 512, Bf1, 512,
            b1 + (size_t)n*2048, nullptr, ffn, 2048, 512);
        // FFN2: single-pass full-K residual store (no atomics) + h16 for next QKV
        gemm16<16,0,2,1><<<dim3(8, 7, 1), 256, 0, stream>>>(ffn, 2048, Bf2, 2048,
            b2 + (size_t)n*512, h, h16, 512, 2048);
    }
    copyk<<<200, 256, 0, stream>>>(h, (float*)d_out, NLOC*512);
}